// Round 14
// baseline (2369.534 us; speedup 1.0000x reference)
//
#include <hip/hip_runtime.h>
#include <hip/hip_bf16.h>

// MomentumDecoder: 2-layer LSTM (B=512,H=512), 256 autoregressive steps.
// Round 14: r12/r13 schedule (1.81ms) + gate-pair wave layout (A-reads /2).
// Wave = (gp: gates {gp,gp+2}, kq: K-quarter). 4-way kq gate-reduce via the
// r9-proven 2-round tree, written into 40KB overlays on bufB (G0, dead window
// 12b->7a) and bufA (G1, dead window 5b->14). Same barrier count as r12.
// Flags/scopes/pv-vmcnt(8)/signal-early-poll-late protocol unchanged.

#define B_ 512
#define H_ 512
#define T_ 256
#define NWG 256
#define NTHR 512

typedef _Float16 half8_t __attribute__((ext_vector_type(8)));
typedef _Float16 half4_t __attribute__((ext_vector_type(4)));
typedef _Float16 half2_t __attribute__((ext_vector_type(2)));
typedef float floatx4 __attribute__((ext_vector_type(4)));

// ---- d_ws layout ----
#define W16_BYTES  (3u * 4u * H_ * H_ * 2u)     // 6 MiB f16 [W_hh0|W_ih1|W_hh1]
#define HBUF_ELEMS (B_ * H_)
#define HBUF_BYTES (HBUF_ELEMS * 2u)
#define H0_OFF   ((size_t)W16_BYTES)
#define H1_OFF   (H0_OFF + 2 * HBUF_BYTES)
#define BAR_OFF  (H1_OFF + 2 * HBUF_BYTES)      // 256 flag ints + 8 rank ints
#define PART_OFF (BAR_OFF + 2048)

__device__ __forceinline__ float sigm_(float x) { return 1.0f / (1.0f + __expf(-x)); }
__device__ __forceinline__ float tanh_(float x) { return 1.0f - 2.0f / (1.0f + __expf(2.0f * x)); }

// ---------------- prep kernels (r6-proven) ----------------
__global__ void prep_weights(const float* __restrict__ whh0,
                             const float* __restrict__ wih1,
                             const float* __restrict__ whh1,
                             _Float16* __restrict__ w16) {
    const int QM = (4 * H_ * H_) / 4;
    int i = blockIdx.x * blockDim.x + threadIdx.x;
    if (i >= 3 * QM) return;
    const float* src; int base;
    if (i < QM)          { src = whh0; base = 0; }
    else if (i < 2 * QM) { src = wih1; base = QM; }
    else                 { src = whh1; base = 2 * QM; }
    float4 v = ((const float4*)src)[i - base];
    half4_t h;
    h[0] = (_Float16)v.x; h[1] = (_Float16)v.y; h[2] = (_Float16)v.z; h[3] = (_Float16)v.w;
    ((half4_t*)w16)[i] = h;
}

__global__ void prep_state(const float* __restrict__ h_in,
                           _Float16* __restrict__ H0, _Float16* __restrict__ H1) {
    int i = blockIdx.x * blockDim.x + threadIdx.x;
    float4 a = ((const float4*)h_in)[i];
    float4 b = ((const float4*)h_in)[(B_ * H_) / 4 + i];
    half4_t ha, hb;
    ha[0] = (_Float16)a.x; ha[1] = (_Float16)a.y; ha[2] = (_Float16)a.z; ha[3] = (_Float16)a.w;
    hb[0] = (_Float16)b.x; hb[1] = (_Float16)b.y; hb[2] = (_Float16)b.z; hb[3] = (_Float16)b.w;
    ((half4_t*)H0)[i] = ha;
    ((half4_t*)H1)[i] = hb;
}

// ---------------- helpers ----------------
// global->LDS 16B, aux=0x01 (SC0: L1 bypass; served from the XCD's L2)
#define GLL16(gptr, lptr) __builtin_amdgcn_global_load_lds( \
    (const __attribute__((address_space(1))) unsigned int*)(gptr), \
    (__attribute__((address_space(3))) unsigned int*)(lptr), 16, 0, 0x01)

// Stage this wave's 8 rows of a 64x512 f16 tile (pre-swizzled source).
__device__ __forceinline__ void stage_rows(const char* gsrc, char* lbuf, int wv, int lane) {
#pragma unroll
    for (int i = 0; i < 8; ++i) {
        int row = wv * 8 + i;
        const char* g_ = gsrc + row * 1024 + (((lane ^ (row & 7)) & 63) << 4);
        GLL16(g_, lbuf + row * 1024);
    }
}

// sc0 16B load (L1 bypass, L2-served)
__device__ __forceinline__ floatx4 load16_sc0(const float* p) {
    floatx4 v;
    asm volatile("global_load_dwordx4 %0, %1, off sc0" : "=v"(v) : "v"(p) : "memory");
    return v;
}

// LDS-only barrier (keeps global_load_lds in flight) / full drain barrier
#define LBAR() asm volatile("s_waitcnt lgkmcnt(0)\n\ts_barrier" ::: "memory")
#define FBAR() asm volatile("s_waitcnt vmcnt(0) lgkmcnt(0)\n\ts_barrier" ::: "memory")

// ---------------- main persistent kernel ----------------
__launch_bounds__(NTHR)
__global__ void lstm_decode(
    const float* __restrict__ c_in,
    const float* __restrict__ wih0, const float* __restrict__ bih0,
    const float* __restrict__ bhh0,
    const float* __restrict__ bih1, const float* __restrict__ bhh1,
    const float* __restrict__ fcw, const float* __restrict__ fcb,
    const _Float16* __restrict__ w16,
    _Float16* __restrict__ Hs0, _Float16* __restrict__ Hs1,
    int* __restrict__ bar, float* __restrict__ part,
    float* __restrict__ outp)
{
    __shared__ __align__(16) char bufA[65536];   // h1 tile; G1-exchange overlay
    __shared__ __align__(16) char bufB[65536];   // h0 tile; G0-exchange overlay
    __shared__ float xrow[64];
    __shared__ int sh_bt, sh_ct;

    const int tid  = (int)threadIdx.x;
    const int lane = tid & 63;
    const int wv   = tid >> 6;    // 0..7
    const int gp_  = wv & 1;      // gate pair -> gates {gp_, gp_+2}
    const int kq   = wv >> 1;     // K quarter (128 wide)
    const int cl   = lane & 15;
    const int kg   = lane >> 4;   // 0..3

    // exchange overlays: [gate][slot][row64][col16+pad]
    float (*gbB)[2][64][20] = (float (*)[2][64][20])bufB;   // G0 (40KB <= 64KB)
    float (*gbA)[2][64][20] = (float (*)[2][64][20])bufA;   // G1

    // ---- XCD-local group formation (r6-proven) ----
    if (tid == 0) {
        unsigned int xcc;
        asm volatile("s_getreg_b32 %0, hwreg(HW_REG_XCC_ID)" : "=s"(xcc));
        int mybt = (int)(xcc & 7u);
        int rank = atomicAdd(&bar[256 + mybt], 1);   // agent-scope
        sh_bt = mybt;
        sh_ct = rank & 31;
    }
    __syncthreads();
    const int bt = sh_bt;
    const int ct = sh_ct;

    // ---- persistent weight fragments: wfX[g][ksg], gate = gp_+2*g ----
    half8_t wf0[2][4], wf1[2][4], wf2[2][4];
    float b0v[2], b1v[2], wxv[2];
#pragma unroll
    for (int g = 0; g < 2; ++g) {
        const int n = (gp_ + 2 * g) * H_ + ct * 16 + cl;
        const _Float16* r0 = w16 + (size_t)n * H_ + kq * 128 + kg * 8;
        const _Float16* r1 = r0 + 4 * H_ * H_;
        const _Float16* r2 = r0 + 8 * H_ * H_;
#pragma unroll
        for (int ksg = 0; ksg < 4; ++ksg) {
            wf0[g][ksg] = *(const half8_t*)(r0 + ksg * 32);
            wf1[g][ksg] = *(const half8_t*)(r1 + ksg * 32);
            wf2[g][ksg] = *(const half8_t*)(r2 + ksg * 32);
        }
        b0v[g] = bih0[n] + bhh0[n];
        b1v[g] = bih1[n] + bhh1[n];
        wxv[g] = wih0[n];
    }
    const float fcb0 = fcb[0];

    // ---- elementwise domain ----
    const int erow = tid >> 3;          // 0..63
    const int ecol = (tid & 7) * 2;     // 0..14 even
    float c0a, c0b, c1a, c1b;
    {
        size_t base0 = (size_t)(bt * 64 + erow) * H_ + ct * 16 + ecol;
        c0a = c_in[base0];                     c0b = c_in[base0 + 1];
        c1a = c_in[(size_t)B_ * H_ + base0];   c1b = c_in[(size_t)B_ * H_ + base0 + 1];
    }
    const float2 fcv = *(const float2*)(fcw + ct * 16 + ecol);

    // A-fragment addressing: row = mt*16+cl, k = kq*128 + ksg*32 + kg*8
    const int abase = cl * 1024 + kq * 256 + kg * 16;
    const int axor  = (cl & 7) << 4;

    int* flagg   = bar + bt * 32;
    float* partg = part + bt * 2048;   // [64 rows][32 ct]
    int ep = 0;

// half-pass over mt in {M0..M1}, both gates of the pair
#define PASSH(bufc, wfm, acc, M0, M1) do {                                    \
    _Pragma("unroll")                                                         \
    for (int ksg = 0; ksg < 4; ++ksg) {                                       \
        _Pragma("unroll")                                                     \
        for (int mt = (M0); mt <= (M1); ++mt) {                               \
            int a_ = (abase + mt * 16384 + ksg * 64) ^ axor;                  \
            half8_t av_ = *(const half8_t*)((bufc) + a_);                     \
            _Pragma("unroll")                                                 \
            for (int g = 0; g < 2; ++g)                                       \
                acc[g][mt] = __builtin_amdgcn_mfma_f32_16x16x32_f16(          \
                    av_, (wfm)[g][ksg], acc[g][mt], 0, 0, 0);                 \
        }                                                                     \
    }                                                                         \
} while (0)

    floatx4 accG0[2][4], accG1[2][4];
    floatx4 pv;   // loop-carried FC-partial load

    // ---- prologue: stage h0(0)+h1(0), PASS0 for t=0 ----
    if (tid < 64) xrow[tid] = 0.f;
    stage_rows((const char*)Hs0 + (size_t)bt * 64 * 1024, bufB, wv, lane);
    stage_rows((const char*)Hs1 + (size_t)bt * 64 * 1024, bufA, wv, lane);
    FBAR();
#pragma unroll
    for (int g = 0; g < 2; ++g)
#pragma unroll
        for (int mt = 0; mt < 4; ++mt) accG0[g][mt] = (floatx4)0.f;
    PASSH(bufB, wf0, accG0, 0, 3);     // G0(0) partial: h0 x W_hh0^T

    for (int t = 0; t < T_; ++t) {
        const size_t pnxt = (size_t)((t + 1) & 1);
        _Float16* h0w = Hs0 + pnxt * HBUF_ELEMS;
        _Float16* h1w = Hs1 + pnxt * HBUF_ELEMS;

        // ---- 1. x-reduce (pv loaded last iter; 8 bufA GLLs younger) ----
        if (t > 0) {
            asm volatile("s_waitcnt vmcnt(8)" : "+v"(pv) :: "memory");
            float xs = (pv[0] + pv[1]) + (pv[2] + pv[3]);
            xs += __shfl_xor(xs, 1);
            xs += __shfl_xor(xs, 2);
            xs += __shfl_xor(xs, 4);
            xs += fcb0;
            if ((tid & 7) == 0) {
                xrow[tid >> 3] = xs;
                if (ct == 0) outp[(size_t)(bt * 64 + (tid >> 3)) * T_ + (t - 1)] = xs;
            }
        }
        LBAR();   // xrow visible; bufB dead (PASS0 consumed it) -> overlay OK

        // ---- 2. G0 exchange: 2-round kq tree into gbB overlay ----
        if (kq & 1) {             // write round: kq1 -> slot0, kq3 -> slot1
#pragma unroll
            for (int g = 0; g < 2; ++g)
#pragma unroll
                for (int mt = 0; mt < 4; ++mt)
#pragma unroll
                    for (int r = 0; r < 4; ++r)
                        gbB[gp_ + 2 * g][kq >> 1][mt * 16 + kg * 4 + r][cl] = accG0[g][mt][r];
        }
        LBAR();
        if (!(kq & 1)) {          // add round: kq0 -> slot0 (+bias+x), kq2 -> slot1
#pragma unroll
            for (int g = 0; g < 2; ++g)
#pragma unroll
                for (int mt = 0; mt < 4; ++mt)
#pragma unroll
                    for (int r = 0; r < 4; ++r) {
                        float v_ = accG0[g][mt][r];
                        if (kq == 0)
                            v_ += __builtin_fmaf(xrow[mt * 16 + kg * 4 + r], wxv[g], b0v[g]);
                        gbB[gp_ + 2 * g][kq >> 1][mt * 16 + kg * 4 + r][cl] += v_;
                    }
        }
        LBAR();

        // ---- 3. EW layer 0 (sum both slots) ----
        {
            float2 iv0 = *(const float2*)&gbB[0][0][erow][ecol];
            float2 iv1 = *(const float2*)&gbB[0][1][erow][ecol];
            float2 fv0 = *(const float2*)&gbB[1][0][erow][ecol];
            float2 fv1 = *(const float2*)&gbB[1][1][erow][ecol];
            float2 gv0 = *(const float2*)&gbB[2][0][erow][ecol];
            float2 gv1 = *(const float2*)&gbB[2][1][erow][ecol];
            float2 ov0 = *(const float2*)&gbB[3][0][erow][ecol];
            float2 ov1 = *(const float2*)&gbB[3][1][erow][ecol];
            float ix = iv0.x + iv1.x, iy = iv0.y + iv1.y;
            float fx = fv0.x + fv1.x, fy = fv0.y + fv1.y;
            float qx = gv0.x + gv1.x, qy = gv0.y + gv1.y;
            float ox = ov0.x + ov1.x, oy = ov0.y + ov1.y;
            float ca = sigm_(fx) * c0a + sigm_(ix) * tanh_(qx);
            float cb = sigm_(fy) * c0b + sigm_(iy) * tanh_(qy);
            c0a = ca; c0b = cb;
            half2_t hh;
            hh[0] = (_Float16)(sigm_(ox) * tanh_(ca));
            hh[1] = (_Float16)(sigm_(oy) * tanh_(cb));
            *(half2_t*)(h0w + (size_t)(bt * 64 + erow) * H_ + ct * 16 + ecol) = hh;
        }

        // ---- 4. SIGNAL A (full drain: h0_new stores + bufA stage) ----
        ++ep;
        FBAR();
        if (tid == 0)
            __hip_atomic_store(&flagg[ct], ep, __ATOMIC_RELAXED, __HIP_MEMORY_SCOPE_AGENT);

        // ---- 5a. PASS2 first half: G1 = h1 x W_hh1^T (mt 0,1) ----
#pragma unroll
        for (int g = 0; g < 2; ++g)
#pragma unroll
            for (int mt = 0; mt < 4; ++mt) accG1[g][mt] = (floatx4)0.f;
        PASSH(bufA, wf2, accG1, 0, 1);

        // ---- 6. POLL A ----
        if (wv == 0) {
            for (;;) {
                int v_ = __hip_atomic_load(&flagg[lane & 31], __ATOMIC_RELAXED,
                                           __HIP_MEMORY_SCOPE_AGENT);
                if (__all(v_ >= ep)) break;
            }
        }
        __syncthreads();

        // ---- 7a. issue stage h0_new -> bufB (overlay consumed at step 3) ----
        stage_rows((const char*)h0w + (size_t)bt * 64 * 1024, bufB, wv, lane);

        // ---- 5b. PASS2 second half (mt 2,3) covers stage latency ----
        PASSH(bufA, wf2, accG1, 2, 3);

        // ---- 7b. drain stage ----
        FBAR();

        // ---- 8. PASS1: G1 += h0_new x W_ih1^T ----
        PASSH(bufB, wf1, accG1, 0, 3);

        // ---- 9. G1 exchange: 2-round kq tree into gbA overlay ----
        if (kq & 1) {
#pragma unroll
            for (int g = 0; g < 2; ++g)
#pragma unroll
                for (int mt = 0; mt < 4; ++mt)
#pragma unroll
                    for (int r = 0; r < 4; ++r)
                        gbA[gp_ + 2 * g][kq >> 1][mt * 16 + kg * 4 + r][cl] = accG1[g][mt][r];
        }
        LBAR();
        if (!(kq & 1)) {
#pragma unroll
            for (int g = 0; g < 2; ++g)
#pragma unroll
                for (int mt = 0; mt < 4; ++mt)
#pragma unroll
                    for (int r = 0; r < 4; ++r) {
                        float v_ = accG1[g][mt][r];
                        if (kq == 0) v_ += b1v[g];
                        gbA[gp_ + 2 * g][kq >> 1][mt * 16 + kg * 4 + r][cl] += v_;
                    }
        }
        LBAR();

        // ---- 10. EW layer 1 + FC partial ----
        {
            float2 iv0 = *(const float2*)&gbA[0][0][erow][ecol];
            float2 iv1 = *(const float2*)&gbA[0][1][erow][ecol];
            float2 fv0 = *(const float2*)&gbA[1][0][erow][ecol];
            float2 fv1 = *(const float2*)&gbA[1][1][erow][ecol];
            float2 gv0 = *(const float2*)&gbA[2][0][erow][ecol];
            float2 gv1 = *(const float2*)&gbA[2][1][erow][ecol];
            float2 ov0 = *(const float2*)&gbA[3][0][erow][ecol];
            float2 ov1 = *(const float2*)&gbA[3][1][erow][ecol];
            float ix = iv0.x + iv1.x, iy = iv0.y + iv1.y;
            float fx = fv0.x + fv1.x, fy = fv0.y + fv1.y;
            float qx = gv0.x + gv1.x, qy = gv0.y + gv1.y;
            float ox = ov0.x + ov1.x, oy = ov0.y + ov1.y;
            float ca = sigm_(fx) * c1a + sigm_(ix) * tanh_(qx);
            float cb = sigm_(fy) * c1b + sigm_(iy) * tanh_(qy);
            c1a = ca; c1b = cb;
            float ha = sigm_(ox) * tanh_(ca);
            float hb = sigm_(oy) * tanh_(cb);
            half2_t hh; hh[0] = (_Float16)ha; hh[1] = (_Float16)hb;
            *(half2_t*)(h1w + (size_t)(bt * 64 + erow) * H_ + ct * 16 + ecol) = hh;
            float ps = __builtin_fmaf(ha, fcv.x, hb * fcv.y);
            ps += __shfl_xor(ps, 1);
            ps += __shfl_xor(ps, 2);
            ps += __shfl_xor(ps, 4);
            if ((tid & 7) == 0)
                partg[(tid >> 3) * 32 + ct] = ps;
        }

        // ---- 11. SIGNAL B (full drain: h1_new + partial stores) ----
        ++ep;
        FBAR();
        if (tid == 0)
            __hip_atomic_store(&flagg[ct], ep, __ATOMIC_RELAXED, __HIP_MEMORY_SCOPE_AGENT);

        // ---- 12a. PASS0(t+1) first half (mt 0,1) ----
#pragma unroll
        for (int g = 0; g < 2; ++g)
#pragma unroll
            for (int mt = 0; mt < 4; ++mt) accG0[g][mt] = (floatx4)0.f;
        PASSH(bufB, wf0, accG0, 0, 1);

        // ---- 13. POLL B ----
        if (wv == 0) {
            for (;;) {
                int v_ = __hip_atomic_load(&flagg[lane & 31], __ATOMIC_RELAXED,
                                           __HIP_MEMORY_SCOPE_AGENT);
                if (__all(v_ >= ep)) break;
            }
        }
        __syncthreads();

        // ---- 14. issue x-partial load + stage h1(t+1) -> bufA ----
        pv = load16_sc0(partg + (tid >> 3) * 32 + (tid & 7) * 4);
        stage_rows((const char*)Hs1 + pnxt * HBUF_BYTES + (size_t)bt * 64 * 1024,
                   bufA, wv, lane);

        // ---- 12b. PASS0(t+1) second half (mt 2,3) covers stage latency ----
        PASSH(bufB, wf0, accG0, 2, 3);
    }

    // ---- epilogue: final x -> outp column T_-1 ----
    {
        asm volatile("s_waitcnt vmcnt(8)" : "+v"(pv) :: "memory");
        float xs = (pv[0] + pv[1]) + (pv[2] + pv[3]);
        xs += __shfl_xor(xs, 1);
        xs += __shfl_xor(xs, 2);
        xs += __shfl_xor(xs, 4);
        xs += fcb0;
        if ((tid & 7) == 0 && ct == 0)
            outp[(size_t)(bt * 64 + (tid >> 3)) * T_ + (T_ - 1)] = xs;
    }
#undef PASSH
#undef LBAR
#undef FBAR
}

extern "C" void kernel_launch(void* const* d_in, const int* in_sizes, int n_in,
                              void* d_out, int out_size, void* d_ws, size_t ws_size,
                              hipStream_t stream) {
    const float* h_in = (const float*)d_in[0];
    const float* c_in = (const float*)d_in[1];
    const float* wih0 = (const float*)d_in[2];
    const float* whh0 = (const float*)d_in[3];
    const float* bih0 = (const float*)d_in[4];
    const float* bhh0 = (const float*)d_in[5];
    const float* wih1 = (const float*)d_in[6];
    const float* whh1 = (const float*)d_in[7];
    const float* bih1 = (const float*)d_in[8];
    const float* bhh1 = (const float*)d_in[9];
    const float* fcw  = (const float*)d_in[10];
    const float* fcb  = (const float*)d_in[11];
    float* out = (float*)d_out;

    char* ws = (char*)d_ws;
    _Float16* w16 = (_Float16*)ws;
    _Float16* Hs0 = (_Float16*)(ws + H0_OFF);
    _Float16* Hs1 = (_Float16*)(ws + H1_OFF);
    int* bar      = (int*)(ws + BAR_OFF);
    float* part   = (float*)(ws + PART_OFF);

    // flags + rank counters must start at 0 (ws poisoned between calls)
    (void)hipMemsetAsync(bar, 0, 2048, stream);

    {
        const int n4 = 3 * (4 * H_ * H_) / 4;
        prep_weights<<<(n4 + 255) / 256, 256, 0, stream>>>(whh0, wih1, whh1, w16);
    }
    prep_state<<<(B_ * H_ / 4) / 256, 256, 0, stream>>>(h_in, Hs0, Hs1);

    lstm_decode<<<NWG, NTHR, 0, stream>>>(c_in, wih0, bih0, bhh0, bih1, bhh1,
                                          fcw, fcb, w16, Hs0, Hs1, bar, part, out);
}

// Round 15
// 1811.087 us; speedup vs baseline: 1.3083x; 1.3083x over previous
//
#include <hip/hip_runtime.h>
#include <hip/hip_bf16.h>

// MomentumDecoder: 2-layer LSTM (B=512,H=512), 256 autoregressive steps.
// Round 15: REVERT to r13 (best verified: 1806us). r14's gate-pair layout
// delivered the predicted conflict reduction (2.18e8 -> 1.34e8) but spilled
// registers (VGPR 124 < 160 live) and regressed — third null/negative result
// on the LDS-traffic lever (r5/r8/r14): the kernel is latency-structural,
// not LDS-throughput-bound. This is the r12 split-phase schedule + r13
// lgkm-only barriers and split passes.

#define B_ 512
#define H_ 512
#define T_ 256
#define NWG 256
#define NTHR 512

typedef _Float16 half8_t __attribute__((ext_vector_type(8)));
typedef _Float16 half4_t __attribute__((ext_vector_type(4)));
typedef _Float16 half2_t __attribute__((ext_vector_type(2)));
typedef float floatx4 __attribute__((ext_vector_type(4)));

// ---- d_ws layout ----
#define W16_BYTES  (3u * 4u * H_ * H_ * 2u)     // 6 MiB f16 [W_hh0|W_ih1|W_hh1]
#define HBUF_ELEMS (B_ * H_)
#define HBUF_BYTES (HBUF_ELEMS * 2u)
#define H0_OFF   ((size_t)W16_BYTES)
#define H1_OFF   (H0_OFF + 2 * HBUF_BYTES)
#define BAR_OFF  (H1_OFF + 2 * HBUF_BYTES)      // 256 flag ints + 8 rank ints
#define PART_OFF (BAR_OFF + 2048)

__device__ __forceinline__ float sigm_(float x) { return 1.0f / (1.0f + __expf(-x)); }
__device__ __forceinline__ float tanh_(float x) { return 1.0f - 2.0f / (1.0f + __expf(2.0f * x)); }

// ---------------- prep kernels (r6-proven) ----------------
__global__ void prep_weights(const float* __restrict__ whh0,
                             const float* __restrict__ wih1,
                             const float* __restrict__ whh1,
                             _Float16* __restrict__ w16) {
    const int QM = (4 * H_ * H_) / 4;
    int i = blockIdx.x * blockDim.x + threadIdx.x;
    if (i >= 3 * QM) return;
    const float* src; int base;
    if (i < QM)          { src = whh0; base = 0; }
    else if (i < 2 * QM) { src = wih1; base = QM; }
    else                 { src = whh1; base = 2 * QM; }
    float4 v = ((const float4*)src)[i - base];
    half4_t h;
    h[0] = (_Float16)v.x; h[1] = (_Float16)v.y; h[2] = (_Float16)v.z; h[3] = (_Float16)v.w;
    ((half4_t*)w16)[i] = h;
}

__global__ void prep_state(const float* __restrict__ h_in,
                           _Float16* __restrict__ H0, _Float16* __restrict__ H1) {
    int i = blockIdx.x * blockDim.x + threadIdx.x;
    float4 a = ((const float4*)h_in)[i];
    float4 b = ((const float4*)h_in)[(B_ * H_) / 4 + i];
    half4_t ha, hb;
    ha[0] = (_Float16)a.x; ha[1] = (_Float16)a.y; ha[2] = (_Float16)a.z; ha[3] = (_Float16)a.w;
    hb[0] = (_Float16)b.x; hb[1] = (_Float16)b.y; hb[2] = (_Float16)b.z; hb[3] = (_Float16)b.w;
    ((half4_t*)H0)[i] = ha;
    ((half4_t*)H1)[i] = hb;
}

// ---------------- helpers ----------------
// global->LDS 16B, aux=0x01 (SC0: L1 bypass; served from the XCD's L2)
#define GLL16(gptr, lptr) __builtin_amdgcn_global_load_lds( \
    (const __attribute__((address_space(1))) unsigned int*)(gptr), \
    (__attribute__((address_space(3))) unsigned int*)(lptr), 16, 0, 0x01)

// Stage this wave's 8 rows of a 64x512 f16 tile (pre-swizzled source).
__device__ __forceinline__ void stage_rows(const char* gsrc, char* lbuf, int wv, int lane) {
#pragma unroll
    for (int i = 0; i < 8; ++i) {
        int row = wv * 8 + i;
        const char* g_ = gsrc + row * 1024 + (((lane ^ (row & 7)) & 63) << 4);
        GLL16(g_, lbuf + row * 1024);
    }
}

// sc0 16B load (L1 bypass, L2-served)
__device__ __forceinline__ floatx4 load16_sc0(const float* p) {
    floatx4 v;
    asm volatile("global_load_dwordx4 %0, %1, off sc0" : "=v"(v) : "v"(p) : "memory");
    return v;
}

// LDS-only barrier: does NOT drain vmcnt (keeps global_load_lds in flight)
#define LBAR() asm volatile("s_waitcnt lgkmcnt(0)\n\ts_barrier" ::: "memory")
// full drain barrier
#define FBAR() asm volatile("s_waitcnt vmcnt(0) lgkmcnt(0)\n\ts_barrier" ::: "memory")

// ---------------- main persistent kernel ----------------
__launch_bounds__(NTHR)
__global__ void lstm_decode(
    const float* __restrict__ c_in,
    const float* __restrict__ wih0, const float* __restrict__ bih0,
    const float* __restrict__ bhh0,
    const float* __restrict__ bih1, const float* __restrict__ bhh1,
    const float* __restrict__ fcw, const float* __restrict__ fcb,
    const _Float16* __restrict__ w16,
    _Float16* __restrict__ Hs0, _Float16* __restrict__ Hs1,
    int* __restrict__ bar, float* __restrict__ part,
    float* __restrict__ outp)
{
    __shared__ __align__(16) char bufA[65536];   // h1 tile
    __shared__ __align__(16) char bufB[65536];   // h0 tile
    __shared__ float gbuf[4][64][20];            // gate exchange, padded
    __shared__ float xrow[64];
    __shared__ int sh_bt, sh_ct;

    const int tid  = (int)threadIdx.x;
    const int lane = tid & 63;
    const int wv   = tid >> 6;    // 0..7
    const int g    = wv & 3;      // gate (i,f,g,o)
    const int kh   = wv >> 2;     // K half
    const int cl   = lane & 15;
    const int kg   = lane >> 4;   // 0..3

    // ---- XCD-local group formation (r6-proven) ----
    if (tid == 0) {
        unsigned int xcc;
        asm volatile("s_getreg_b32 %0, hwreg(HW_REG_XCC_ID)" : "=s"(xcc));
        int mybt = (int)(xcc & 7u);
        int rank = atomicAdd(&bar[256 + mybt], 1);   // agent-scope
        sh_bt = mybt;
        sh_ct = rank & 31;
    }
    __syncthreads();
    const int bt = sh_bt;
    const int ct = sh_ct;

    // ---- persistent weight fragments (96 VGPRs) ----
    const int n = g * H_ + ct * 16 + cl;
    half8_t wf0[8], wf1[8], wf2[8];
    {
        const _Float16* r0 = w16 + (size_t)n * H_ + kh * 256 + kg * 8;
        const _Float16* r1 = r0 + 4 * H_ * H_;
        const _Float16* r2 = r0 + 8 * H_ * H_;
#pragma unroll
        for (int ksg = 0; ksg < 8; ++ksg) {
            wf0[ksg] = *(const half8_t*)(r0 + ksg * 32);
            wf1[ksg] = *(const half8_t*)(r1 + ksg * 32);
            wf2[ksg] = *(const half8_t*)(r2 + ksg * 32);
        }
    }
    const float b0   = bih0[n] + bhh0[n];
    const float b1   = bih1[n] + bhh1[n];
    const float wx   = wih0[n];
    const float fcb0 = fcb[0];

    // ---- elementwise domain ----
    const int erow = tid >> 3;          // 0..63
    const int ecol = (tid & 7) * 2;     // 0..14 even
    float c0a, c0b, c1a, c1b;
    {
        size_t base0 = (size_t)(bt * 64 + erow) * H_ + ct * 16 + ecol;
        c0a = c_in[base0];                     c0b = c_in[base0 + 1];
        c1a = c_in[(size_t)B_ * H_ + base0];   c1b = c_in[(size_t)B_ * H_ + base0 + 1];
    }
    const float2 fcv = *(const float2*)(fcw + ct * 16 + ecol);

    const int abase = cl * 1024 + kh * 512 + kg * 16;
    const int axor  = (cl & 7) << 4;

    int* flagg   = bar + bt * 32;
    float* partg = part + bt * 2048;   // [64 rows][32 ct]
    int ep = 0;

// half-pass over mt in {M0, M1}
#define PASSH(bufc, wf, acc, M0, M1) do {                                     \
    _Pragma("unroll")                                                         \
    for (int ksg = 0; ksg < 8; ++ksg) {                                       \
        _Pragma("unroll")                                                     \
        for (int mt = (M0); mt <= (M1); ++mt) {                               \
            int a_ = (abase + mt * 16384 + ksg * 64) ^ axor;                  \
            half8_t av_ = *(const half8_t*)((bufc) + a_);                     \
            acc[mt] = __builtin_amdgcn_mfma_f32_16x16x32_f16(av_, (wf)[ksg],  \
                                                             acc[mt], 0, 0, 0); \
        }                                                                     \
    }                                                                         \
} while (0)

    floatx4 accG0[4], accG1[4];
    floatx4 pv;   // loop-carried FC-partial load

    // ---- prologue: stage h0(0)+h1(0), PASS0 for t=0 ----
    if (tid < 64) xrow[tid] = 0.f;
    stage_rows((const char*)Hs0 + (size_t)bt * 64 * 1024, bufB, wv, lane);
    stage_rows((const char*)Hs1 + (size_t)bt * 64 * 1024, bufA, wv, lane);
    FBAR();
#pragma unroll
    for (int mt = 0; mt < 4; ++mt) accG0[mt] = (floatx4)0.f;
    PASSH(bufB, wf0, accG0, 0, 3);     // G0(0) partial: h0 x W_hh0^T

    for (int t = 0; t < T_; ++t) {
        const size_t pnxt = (size_t)((t + 1) & 1);
        _Float16* h0w = Hs0 + pnxt * HBUF_ELEMS;
        _Float16* h1w = Hs1 + pnxt * HBUF_ELEMS;

        // ---- 1. x-reduce (pv loaded last iter; 8 bufA GLLs younger) ----
        if (t > 0) {
            asm volatile("s_waitcnt vmcnt(8)" : "+v"(pv) :: "memory");
            float xs = (pv[0] + pv[1]) + (pv[2] + pv[3]);
            xs += __shfl_xor(xs, 1);
            xs += __shfl_xor(xs, 2);
            xs += __shfl_xor(xs, 4);
            xs += fcb0;
            if ((tid & 7) == 0) {
                xrow[tid >> 3] = xs;
                if (ct == 0) outp[(size_t)(bt * 64 + (tid >> 3)) * T_ + (t - 1)] = xs;
            }
        }
        LBAR();   // xrow visible; bufA stage GLLs stay in flight

        // ---- 2. exchange G0 (LDS-only barriers) ----
        if (kh == 0) {
#pragma unroll
            for (int mt = 0; mt < 4; ++mt)
#pragma unroll
                for (int r = 0; r < 4; ++r)
                    gbuf[g][mt * 16 + kg * 4 + r][cl] =
                        accG0[mt][r] + __builtin_fmaf(xrow[mt * 16 + kg * 4 + r], wx, b0);
        }
        LBAR();
        if (kh == 1) {
#pragma unroll
            for (int mt = 0; mt < 4; ++mt)
#pragma unroll
                for (int r = 0; r < 4; ++r)
                    gbuf[g][mt * 16 + kg * 4 + r][cl] += accG0[mt][r];
        }
        LBAR();

        // ---- 3. EW layer 0 ----
        {
            float2 iv = *(const float2*)&gbuf[0][erow][ecol];
            float2 fv = *(const float2*)&gbuf[1][erow][ecol];
            float2 gv = *(const float2*)&gbuf[2][erow][ecol];
            float2 ov = *(const float2*)&gbuf[3][erow][ecol];
            float ca = sigm_(fv.x) * c0a + sigm_(iv.x) * tanh_(gv.x);
            float cb = sigm_(fv.y) * c0b + sigm_(iv.y) * tanh_(gv.y);
            c0a = ca; c0b = cb;
            half2_t hh;
            hh[0] = (_Float16)(sigm_(ov.x) * tanh_(ca));
            hh[1] = (_Float16)(sigm_(ov.y) * tanh_(cb));
            *(half2_t*)(h0w + (size_t)(bt * 64 + erow) * H_ + ct * 16 + ecol) = hh;
        }

        // ---- 4. SIGNAL A (full drain: h0_new stores + bufA stage) ----
        ++ep;
        FBAR();
        if (tid == 0)
            __hip_atomic_store(&flagg[ct], ep, __ATOMIC_RELAXED, __HIP_MEMORY_SCOPE_AGENT);

        // ---- 5a. PASS2 first half: G1 = bias + h1 x W_hh1^T (mt 0,1) ----
#pragma unroll
        for (int mt = 0; mt < 4; ++mt) {
            if (kh == 0) {
#pragma unroll
                for (int r = 0; r < 4; ++r) accG1[mt][r] = b1;
            } else {
                accG1[mt] = (floatx4)0.f;
            }
        }
        PASSH(bufA, wf2, accG1, 0, 1);

        // ---- 6. POLL A ----
        if (wv == 0) {
            for (;;) {
                int v_ = __hip_atomic_load(&flagg[lane & 31], __ATOMIC_RELAXED,
                                           __HIP_MEMORY_SCOPE_AGENT);
                if (__all(v_ >= ep)) break;
            }
        }
        __syncthreads();

        // ---- 7a. issue stage h0_new -> bufB ----
        stage_rows((const char*)h0w + (size_t)bt * 64 * 1024, bufB, wv, lane);

        // ---- 5b. PASS2 second half (mt 2,3) covers stage latency ----
        PASSH(bufA, wf2, accG1, 2, 3);

        // ---- 7b. drain stage ----
        FBAR();

        // ---- 8. PASS1: G1 += h0_new x W_ih1^T ----
        PASSH(bufB, wf1, accG1, 0, 3);

        // ---- 9. exchange G1 ----
        if (kh == 0) {
#pragma unroll
            for (int mt = 0; mt < 4; ++mt)
#pragma unroll
                for (int r = 0; r < 4; ++r)
                    gbuf[g][mt * 16 + kg * 4 + r][cl] = accG1[mt][r];
        }
        LBAR();
        if (kh == 1) {
#pragma unroll
            for (int mt = 0; mt < 4; ++mt)
#pragma unroll
                for (int r = 0; r < 4; ++r)
                    gbuf[g][mt * 16 + kg * 4 + r][cl] += accG1[mt][r];
        }
        LBAR();

        // ---- 10. EW layer 1 + FC partial ----
        {
            float2 iv = *(const float2*)&gbuf[0][erow][ecol];
            float2 fv = *(const float2*)&gbuf[1][erow][ecol];
            float2 gv = *(const float2*)&gbuf[2][erow][ecol];
            float2 ov = *(const float2*)&gbuf[3][erow][ecol];
            float ca = sigm_(fv.x) * c1a + sigm_(iv.x) * tanh_(gv.x);
            float cb = sigm_(fv.y) * c1b + sigm_(iv.y) * tanh_(gv.y);
            c1a = ca; c1b = cb;
            float ha = sigm_(ov.x) * tanh_(ca);
            float hb = sigm_(ov.y) * tanh_(cb);
            half2_t hh; hh[0] = (_Float16)ha; hh[1] = (_Float16)hb;
            *(half2_t*)(h1w + (size_t)(bt * 64 + erow) * H_ + ct * 16 + ecol) = hh;
            float ps = __builtin_fmaf(ha, fcv.x, hb * fcv.y);
            ps += __shfl_xor(ps, 1);
            ps += __shfl_xor(ps, 2);
            ps += __shfl_xor(ps, 4);
            if ((tid & 7) == 0)
                partg[(tid >> 3) * 32 + ct] = ps;
        }

        // ---- 11. SIGNAL B (full drain: h1_new + partial stores) ----
        ++ep;
        FBAR();
        if (tid == 0)
            __hip_atomic_store(&flagg[ct], ep, __ATOMIC_RELAXED, __HIP_MEMORY_SCOPE_AGENT);

        // ---- 12a. PASS0(t+1) first half (mt 0,1) ----
#pragma unroll
        for (int mt = 0; mt < 4; ++mt) accG0[mt] = (floatx4)0.f;
        PASSH(bufB, wf0, accG0, 0, 1);

        // ---- 13. POLL B ----
        if (wv == 0) {
            for (;;) {
                int v_ = __hip_atomic_load(&flagg[lane & 31], __ATOMIC_RELAXED,
                                           __HIP_MEMORY_SCOPE_AGENT);
                if (__all(v_ >= ep)) break;
            }
        }
        __syncthreads();

        // ---- 14. issue x-partial load + stage h1(t+1) -> bufA ----
        pv = load16_sc0(partg + (tid >> 3) * 32 + (tid & 7) * 4);
        stage_rows((const char*)Hs1 + pnxt * HBUF_BYTES + (size_t)bt * 64 * 1024,
                   bufA, wv, lane);

        // ---- 12b. PASS0(t+1) second half (mt 2,3) covers stage latency ----
        PASSH(bufB, wf0, accG0, 2, 3);
    }

    // ---- epilogue: final x -> outp column T_-1 ----
    {
        asm volatile("s_waitcnt vmcnt(8)" : "+v"(pv) :: "memory");
        float xs = (pv[0] + pv[1]) + (pv[2] + pv[3]);
        xs += __shfl_xor(xs, 1);
        xs += __shfl_xor(xs, 2);
        xs += __shfl_xor(xs, 4);
        xs += fcb0;
        if ((tid & 7) == 0 && ct == 0)
            outp[(size_t)(bt * 64 + (tid >> 3)) * T_ + (T_ - 1)] = xs;
    }
#undef PASSH
#undef LBAR
#undef FBAR
}

extern "C" void kernel_launch(void* const* d_in, const int* in_sizes, int n_in,
                              void* d_out, int out_size, void* d_ws, size_t ws_size,
                              hipStream_t stream) {
    const float* h_in = (const float*)d_in[0];
    const float* c_in = (const float*)d_in[1];
    const float* wih0 = (const float*)d_in[2];
    const float* whh0 = (const float*)d_in[3];
    const float* bih0 = (const float*)d_in[4];
    const float* bhh0 = (const float*)d_in[5];
    const float* wih1 = (const float*)d_in[6];
    const float* whh1 = (const float*)d_in[7];
    const float* bih1 = (const float*)d_in[8];
    const float* bhh1 = (const float*)d_in[9];
    const float* fcw  = (const float*)d_in[10];
    const float* fcb  = (const float*)d_in[11];
    float* out = (float*)d_out;

    char* ws = (char*)d_ws;
    _Float16* w16 = (_Float16*)ws;
    _Float16* Hs0 = (_Float16*)(ws + H0_OFF);
    _Float16* Hs1 = (_Float16*)(ws + H1_OFF);
    int* bar      = (int*)(ws + BAR_OFF);
    float* part   = (float*)(ws + PART_OFF);

    // flags + rank counters must start at 0 (ws poisoned between calls)
    (void)hipMemsetAsync(bar, 0, 2048, stream);

    {
        const int n4 = 3 * (4 * H_ * H_) / 4;
        prep_weights<<<(n4 + 255) / 256, 256, 0, stream>>>(whh0, wih1, whh1, w16);
    }
    prep_state<<<(B_ * H_ / 4) / 256, 256, 0, stream>>>(h_in, Hs0, Hs1);

    lstm_decode<<<NWG, NTHR, 0, stream>>>(c_in, wih0, bih0, bhh0, bih1, bhh1,
                                          fcw, fcb, w16, Hs0, Hs1, bar, part, out);
}